// Round 1
// baseline (250.189 us; speedup 1.0000x reference)
//
#include <hip/hip_runtime.h>

// Problem: proj = einsum('bit,ih->tbh', x, W); then per-(b,h) sequential scan:
//   h = relu(p_t + 0.8*h*(1-y)); z = h + bias; y = (z>1) ? z : 0;  return final y.
// B=64, I=K=512, T=512, H=1024, fp32 in/out.
//
// Strategy: fused kernel, one block per (b, 128-wide h tile). For each 64-wide
// t tile: GEMM via fp16 split-2 MFMA (x=xh+xl/4096, W=wh+wl/4096; 3 passes ->
// ~fp32 precision, needed because the scan thresholds at z>1 and a flipped
// branch costs ~1.0 > the 0.94 absmax budget), result to LDS, then 64 scan
// steps with chain state (hs, ys) in registers of threads 0..127.

#define NB 64
#define NK 512
#define NT 512
#define NH 1024

#define HT 128   // h per block
#define TT 64    // t per tile
#define KK 32    // k per staging step (== MFMA K)
#define KPAD 40  // halfs per LDS row: 32 + 8 pad -> 80B rows, 16B aligned
#define PPAD 130 // floats per P row: 128 + 2 pad

typedef _Float16 h4_t __attribute__((ext_vector_type(4)));
typedef _Float16 h8_t __attribute__((ext_vector_type(8)));
typedef float    f4_t __attribute__((ext_vector_type(4)));

__global__ __launch_bounds__(512) void fused_proj_scan(
    const float* __restrict__ x,     // [NB][NK][NT]
    const float* __restrict__ W,     // [NK][NH]
    const float* __restrict__ bias,  // [NH]
    float* __restrict__ out)         // [NB][NH]
{
    __shared__ _Float16 Ahi[TT][KPAD];
    __shared__ _Float16 Alo[TT][KPAD];
    __shared__ _Float16 Bhi[HT][KPAD];
    __shared__ _Float16 Blo[HT][KPAD];
    __shared__ float    P[TT][PPAD];
    // LDS total: 10240 + 20480 + 33280 = 64000 B

    const int tid  = threadIdx.x;
    const int lane = tid & 63;
    const int wid  = tid >> 6;   // 0..7
    const int l15  = lane & 15;
    const int lq   = lane >> 4;  // quad 0..3

    const int b  = blockIdx.x;        // 0..63
    const int h0 = blockIdx.y * HT;   // 0..896

    // wave grid 2(m) x 4(n), each wave owns a 32x32 output tile
    const int wm = wid >> 2;  // 0..1
    const int wn = wid & 3;   // 0..3

    // A staging map: thread -> (m = tid&63, k-group = tid>>6 covering 4 k)
    const int am  = tid & 63;
    const int akg = tid >> 6;   // k = akg*4 + j
    // B staging map: thread -> (n = tid&127, kh = tid>>7 covering 8 k)
    const int bn  = tid & 127;
    const int bkh = tid >> 7;   // k = bkh*8 + jj*4 + j

    const float* xb = x + (size_t)b * (NK * NT);

    float hs = 0.0f, ys = 0.0f;   // chain state (threads 0..127)
    float bv = 0.0f;
    if (tid < HT) bv = bias[h0 + tid];

    const float SCALE = 4096.0f;          // 2^12: keeps fp16 low parts normal
    const float INV_SCALE = 1.0f / 4096.0f;

    for (int tt0 = 0; tt0 < NT; tt0 += TT) {
        f4_t acc_hi[2][2], acc_lo[2][2];
        #pragma unroll
        for (int mi = 0; mi < 2; ++mi)
            #pragma unroll
            for (int ni = 0; ni < 2; ++ni) {
                f4_t z = {0.0f, 0.0f, 0.0f, 0.0f};
                acc_hi[mi][ni] = z;
                acc_lo[mi][ni] = z;
            }

        for (int k0 = 0; k0 < NK; k0 += KK) {
            // ---- stage A (x) tile: [TT m][KK k], split fp16, k-contiguous ----
            {
                float v[4];
                #pragma unroll
                for (int j = 0; j < 4; ++j)
                    v[j] = xb[(k0 + akg * 4 + j) * NT + tt0 + am]; // coalesced in am
                h4_t hi, lo;
                #pragma unroll
                for (int j = 0; j < 4; ++j) {
                    _Float16 hh = (_Float16)v[j];
                    hi[j] = hh;
                    lo[j] = (_Float16)((v[j] - (float)hh) * SCALE);
                }
                *(h4_t*)(&Ahi[am][akg * 4]) = hi;
                *(h4_t*)(&Alo[am][akg * 4]) = lo;
            }
            // ---- stage B (W) tile: [HT n][KK k], split fp16, k-contiguous ----
            {
                #pragma unroll
                for (int jj = 0; jj < 2; ++jj) {
                    h4_t hi, lo;
                    #pragma unroll
                    for (int j = 0; j < 4; ++j) {
                        float v = W[(k0 + bkh * 8 + jj * 4 + j) * NH + h0 + bn]; // coalesced in bn
                        _Float16 hh = (_Float16)v;
                        hi[j] = hh;
                        lo[j] = (_Float16)((v - (float)hh) * SCALE);
                    }
                    *(h4_t*)(&Bhi[bn][bkh * 8 + jj * 4]) = hi;
                    *(h4_t*)(&Blo[bn][bkh * 8 + jj * 4]) = lo;
                }
            }
            __syncthreads();

            // ---- fragments + MFMA (A[m=lane&15][k=quad*8+j], B mirrored) ----
            h8_t bh[2], bl[2];
            #pragma unroll
            for (int ni = 0; ni < 2; ++ni) {
                const int n = wn * 32 + ni * 16 + l15;
                bh[ni] = *(const h8_t*)(&Bhi[n][lq * 8]);
                bl[ni] = *(const h8_t*)(&Blo[n][lq * 8]);
            }
            #pragma unroll
            for (int mi = 0; mi < 2; ++mi) {
                const int m = wm * 32 + mi * 16 + l15;
                h8_t ah = *(const h8_t*)(&Ahi[m][lq * 8]);
                h8_t al = *(const h8_t*)(&Alo[m][lq * 8]);
                #pragma unroll
                for (int ni = 0; ni < 2; ++ni) {
                    acc_hi[mi][ni] = __builtin_amdgcn_mfma_f32_16x16x32_f16(ah, bh[ni], acc_hi[mi][ni], 0, 0, 0);
                    acc_lo[mi][ni] = __builtin_amdgcn_mfma_f32_16x16x32_f16(ah, bl[ni], acc_lo[mi][ni], 0, 0, 0);
                    acc_lo[mi][ni] = __builtin_amdgcn_mfma_f32_16x16x32_f16(al, bh[ni], acc_lo[mi][ni], 0, 0, 0);
                }
            }
            __syncthreads();
        }

        // ---- write P tile (C/D layout: col=lane&15, row=quad*4+reg) ----
        #pragma unroll
        for (int mi = 0; mi < 2; ++mi)
            #pragma unroll
            for (int ni = 0; ni < 2; ++ni)
                #pragma unroll
                for (int r = 0; r < 4; ++r) {
                    const int row = wm * 32 + mi * 16 + lq * 4 + r;
                    const int col = wn * 32 + ni * 16 + l15;
                    P[row][col] = acc_hi[mi][ni][r] + acc_lo[mi][ni][r] * INV_SCALE;
                }
        __syncthreads();

        // ---- scan TT steps; threads 0..127 own chains, others fall through ----
        if (tid < HT) {
            #pragma unroll 8
            for (int m = 0; m < TT; ++m) {
                float p = P[m][tid];
                float pre = p + 0.8f * hs * (1.0f - ys);
                hs = pre > 0.0f ? pre : 0.0f;
                float z = hs + bv;
                ys = (z > 1.0f) ? z : 0.0f;
            }
        }
        __syncthreads();
    }

    if (tid < HT)
        out[(size_t)b * NH + h0 + tid] = ys;
}

extern "C" void kernel_launch(void* const* d_in, const int* in_sizes, int n_in,
                              void* d_out, int out_size, void* d_ws, size_t ws_size,
                              hipStream_t stream) {
    const float* x    = (const float*)d_in[0];  // 64*512*512
    const float* W    = (const float*)d_in[1];  // 512*1024
    const float* bias = (const float*)d_in[2];  // 1024
    float* out = (float*)d_out;                 // 64*1024

    dim3 grid(NB, NH / HT);   // 64 x 8 = 512 blocks
    fused_proj_scan<<<grid, 512, 0, stream>>>(x, W, bias, out);
}

// Round 2
// 194.108 us; speedup vs baseline: 1.2889x; 1.2889x over previous
//
#include <hip/hip_runtime.h>
#include <stdint.h>

// proj = einsum('bit,ih->tbh', x, W); scan: h=relu(p+0.8h(1-y)); y=thr(h+b,1).
// B=64, K=512, T=512, H=1024 fp32. Output: final y (64x1024).
//
// R2: split/transpose moved to pre-pass (ws), main kernel stages pre-split
// fp16 hi/lo tiles via global_load_lds (width 16) into XOR-swizzled unpadded
// LDS; 4 waves x (64t x 64h) per block, fp16 split-2 3-pass MFMA (validated
// r1: absmax 0.031). ws layout: xhi | xlo | whi | wlo = 69.2 MB.

#define NB 64
#define NK 512
#define NT 512
#define NH 1024

#define HT 128     // h per block
#define TTILE 128  // t per block tile
#define KK 32      // k per step

typedef _Float16 h8_t __attribute__((ext_vector_type(8)));
typedef float    f4_t __attribute__((ext_vector_type(4)));

#define AS1 __attribute__((address_space(1)))
#define AS3 __attribute__((address_space(3)))

__device__ __forceinline__ void async_copy16(const _Float16* g, _Float16* l) {
    __builtin_amdgcn_global_load_lds((const AS1 uint32_t*)g, (AS3 uint32_t*)l, 16, 0, 0);
}

// ---------------- pre-pass: fp32 [bb*512 + k][C] -> fp16 hi/lo [bb*16+kt][c][32],
// chunk order within each row swizzled: chunk ck stored at ck ^ ((c>>1)&3) ----
__global__ __launch_bounds__(256) void split_transpose(
    const float* __restrict__ src, _Float16* __restrict__ dhi,
    _Float16* __restrict__ dlo, int C)
{
    __shared__ float Tt[32][260];  // 32 k-rows x 256 cols (+pad)
    const int tid = threadIdx.x;
    const int c0  = blockIdx.x * 256;
    const int kt  = blockIdx.y;
    const int bb  = blockIdx.z;

    const float* s0 = src + ((size_t)(bb * 512 + kt * 32)) * C + c0;
    #pragma unroll
    for (int r = 0; r < 8; ++r) {
        int idx = tid + r * 256;        // 0..2047
        int row = idx >> 6;             // 0..31
        int c4  = (idx & 63) * 4;       // 0..252
        f4_t v = *(const f4_t*)(s0 + (size_t)row * C + c4);
        *(f4_t*)(&Tt[row][c4]) = v;     // 260*4B rows: 16B aligned
    }
    __syncthreads();

    const size_t dbase = (size_t)(bb * 16 + kt) * C * 32;  // halfs
    #pragma unroll
    for (int r = 0; r < 4; ++r) {
        int idx = tid + r * 256;        // 0..1023
        int t   = idx >> 2;             // 0..255 (local col)
        int ck  = idx & 3;              // k-octet
        int cg  = c0 + t;               // global col
        h8_t hi, lo;
        #pragma unroll
        for (int j = 0; j < 8; ++j) {
            float v = Tt[ck * 8 + j][t];
            _Float16 hh = (_Float16)v;
            hi[j] = hh;
            lo[j] = (_Float16)((v - (float)hh) * 4096.0f);
        }
        int ckp = ck ^ ((cg >> 1) & 3);
        size_t off = dbase + (size_t)cg * 32 + ckp * 8;
        *(h8_t*)(dhi + off) = hi;
        *(h8_t*)(dlo + off) = lo;
    }
}

// ---------------- main fused kernel ----------------
__global__ __launch_bounds__(256, 2) void fused_main(
    const _Float16* __restrict__ xhi, const _Float16* __restrict__ xlo,
    const _Float16* __restrict__ whi, const _Float16* __restrict__ wlo,
    const float* __restrict__ bias, float* __restrict__ out)
{
    // unpadded, chunk-swizzled tiles (row = t or h local, 32 halfs/row)
    __shared__ __align__(16) _Float16 Ahi[TTILE * KK];  // 8 KB
    __shared__ __align__(16) _Float16 Alo[TTILE * KK];
    __shared__ __align__(16) _Float16 Bhi[HT * KK];
    __shared__ __align__(16) _Float16 Blo[HT * KK];
    __shared__ float P[64][130];                         // 33,280 B
    // total 66,048 B -> 2 blocks/CU

    const int tid  = threadIdx.x;
    const int lane = tid & 63;
    const int wid  = tid >> 6;     // 0..3
    const int l15  = lane & 15;
    const int lq   = lane >> 4;    // 0..3
    const int wm   = wid >> 1;     // t half: 0..1
    const int wn   = wid & 1;      // h half: 0..1

    const int b  = blockIdx.x;
    const int h0 = blockIdx.y * HT;

    // fragment LDS offsets (halfs); swizzle bits are lane-constant
    const int sw   = (l15 >> 1) & 3;
    const int aoff = ((wm * 64 + l15) * 4 + (lq ^ sw)) * 8;  // + mi*512
    const int boff = ((wn * 64 + l15) * 4 + (lq ^ sw)) * 8;  // + ni*512

    const int ch0 = wid * 128 + lane;  // staging chunks: ch0, ch0+64

    float hs = 0.0f, ys = 0.0f, bv = 0.0f;
    if (tid < HT) bv = bias[h0 + tid];

    const float INV_SCALE = 1.0f / 4096.0f;

    f4_t acch[4][4], accl[4][4];

    for (int tt0 = 0; tt0 < NT; tt0 += TTILE) {
        #pragma unroll
        for (int mi = 0; mi < 4; ++mi)
            #pragma unroll
            for (int ni = 0; ni < 4; ++ni) {
                f4_t z = {0.f, 0.f, 0.f, 0.f};
                acch[mi][ni] = z;
                accl[mi][ni] = z;
            }

        for (int kt = 0; kt < NK / KK; ++kt) {
            const _Float16* ga_hi = xhi + ((size_t)(b * 16 + kt) * NT + tt0) * KK;
            const _Float16* ga_lo = xlo + ((size_t)(b * 16 + kt) * NT + tt0) * KK;
            const _Float16* gb_hi = whi + ((size_t)kt * NH + h0) * KK;
            const _Float16* gb_lo = wlo + ((size_t)kt * NH + h0) * KK;

            #pragma unroll
            for (int c = 0; c < 2; ++c) {
                const int ch = ch0 + c * 64;
                async_copy16(ga_hi + ch * 8, &Ahi[ch * 8]);
                async_copy16(ga_lo + ch * 8, &Alo[ch * 8]);
                async_copy16(gb_hi + ch * 8, &Bhi[ch * 8]);
                async_copy16(gb_lo + ch * 8, &Blo[ch * 8]);
            }
            __syncthreads();

            h8_t bh[4], bl[4];
            #pragma unroll
            for (int ni = 0; ni < 4; ++ni) {
                bh[ni] = *(const h8_t*)(&Bhi[boff + ni * 512]);
                bl[ni] = *(const h8_t*)(&Blo[boff + ni * 512]);
            }
            #pragma unroll
            for (int mi = 0; mi < 4; ++mi) {
                h8_t ah = *(const h8_t*)(&Ahi[aoff + mi * 512]);
                h8_t al = *(const h8_t*)(&Alo[aoff + mi * 512]);
                #pragma unroll
                for (int ni = 0; ni < 4; ++ni) {
                    acch[mi][ni] = __builtin_amdgcn_mfma_f32_16x16x32_f16(ah, bh[ni], acch[mi][ni], 0, 0, 0);
                    accl[mi][ni] = __builtin_amdgcn_mfma_f32_16x16x32_f16(ah, bl[ni], accl[mi][ni], 0, 0, 0);
                    accl[mi][ni] = __builtin_amdgcn_mfma_f32_16x16x32_f16(al, bh[ni], accl[mi][ni], 0, 0, 0);
                }
            }
            __syncthreads();
        }

        // epilogue: two 64-t halves; C/D layout col=l15, row=lq*4+r
        #pragma unroll
        for (int half = 0; half < 2; ++half) {
            if (wm == half) {
                #pragma unroll
                for (int mi = 0; mi < 4; ++mi)
                    #pragma unroll
                    for (int ni = 0; ni < 4; ++ni)
                        #pragma unroll
                        for (int r = 0; r < 4; ++r) {
                            const int row = mi * 16 + lq * 4 + r;
                            const int col = wn * 64 + ni * 16 + l15;
                            P[row][col] = acch[mi][ni][r] + accl[mi][ni][r] * INV_SCALE;
                        }
            }
            __syncthreads();
            if (tid < HT) {
                #pragma unroll 8
                for (int m = 0; m < 64; ++m) {
                    float p = P[m][tid];
                    float pre = p + 0.8f * hs * (1.0f - ys);
                    hs = pre > 0.0f ? pre : 0.0f;
                    float z = hs + bv;
                    ys = (z > 1.0f) ? z : 0.0f;
                }
            }
            __syncthreads();
        }
    }

    if (tid < HT)
        out[(size_t)b * NH + h0 + tid] = ys;
}

extern "C" void kernel_launch(void* const* d_in, const int* in_sizes, int n_in,
                              void* d_out, int out_size, void* d_ws, size_t ws_size,
                              hipStream_t stream) {
    const float* x    = (const float*)d_in[0];  // [64][512][512]
    const float* W    = (const float*)d_in[1];  // [512][1024]
    const float* bias = (const float*)d_in[2];  // [1024]
    float* out = (float*)d_out;

    _Float16* xhi = (_Float16*)d_ws;
    _Float16* xlo = xhi + (size_t)NB * NK * NT;
    _Float16* whi = xlo + (size_t)NB * NK * NT;
    _Float16* wlo = whi + (size_t)NK * NH;
    // total ws use: 2*33.55MB + 2*1MB = 69.2 MB

    split_transpose<<<dim3(NT / 256, NK / 32, NB), 256, 0, stream>>>(x, xhi, xlo, NT);
    split_transpose<<<dim3(NH / 256, NK / 32, 1), 256, 0, stream>>>(W, whi, wlo, NH);
    fused_main<<<dim3(NB, NH / HT), 256, 0, stream>>>(xhi, xlo, whi, wlo, bias, out);
}

// Round 5
// 192.137 us; speedup vs baseline: 1.3021x; 1.0103x over previous
//
#include <hip/hip_runtime.h>
#include <stdint.h>

// proj = einsum('bit,ih->tbh', x, W); scan: h=relu(p+0.8h(1-y)); y=thr(h+b,1).
// B=64, K=512, T=512, H=1024 fp32. Output: final y (64x1024).
//
// R5: bisection round. R3/R4 failed identically (~36 absmax) despite a
// numerics fix; pre-pass layout trace-verified byte-identical to R2's
// (which passed). Remaining suspect: R3/R4's bottom-of-loop conditional
// stage() consumed across a loop back-edge — if the compiler misses the
// vmcnt drain before s_barrier there, ds_reads race the in-flight
// global_load_lds. Fix: restore R2's proven k-loop shape (stage at top,
// consume immediately) + explicit s_waitcnt(0) before k-loop barriers.
// Keep the R3 perf levers: 8 waves, 64x128 wave tiles, single fp32 acc
// (inputs pre-scaled 2^6; P = acc/4096), 256t x 256h block, grid 64x4.

#define NB 64
#define NK 512
#define NT 512
#define NH 1024

#define TB 256     // t per block tile
#define HB 256     // h per block tile
#define KK 32      // k per step

typedef _Float16 h8_t __attribute__((ext_vector_type(8)));
typedef float    f4_t __attribute__((ext_vector_type(4)));

#define AS1 __attribute__((address_space(1)))
#define AS3 __attribute__((address_space(3)))

__device__ __forceinline__ void async_copy16(const _Float16* g, _Float16* l) {
    __builtin_amdgcn_global_load_lds((const AS1 uint32_t*)g, (AS3 uint32_t*)l, 16, 0, 0);
}

// explicit full drain + barrier: belt-and-suspenders vs compiler waitcnt
// insertion around global_load_lds (suspected R3/R4 failure mode)
__device__ __forceinline__ void wait_all_barrier() {
    __builtin_amdgcn_s_waitcnt(0);   // vmcnt(0) expcnt(0) lgkmcnt(0)
    __syncthreads();
}

// ---- pre-pass: fp32 [bb*512 + k][C] -> fp16 hi/lo in fragment order
// [bb*16+kt][c][32], chunk ck stored at position ck ^ ((c>>1)&3).
// Values pre-scaled by 2^6 so the fp16 residual (lo) stays normal-range.
__global__ __launch_bounds__(256) void split_fragorder(
    const float* __restrict__ src, _Float16* __restrict__ dhi,
    _Float16* __restrict__ dlo, int C)
{
    const int c  = threadIdx.x >> 2;   // 0..63
    const int ck = threadIdx.x & 3;    // k-octet
    const int c0 = blockIdx.x * 64;
    const int kt = blockIdx.y;
    const int bb = blockIdx.z;

    const int cg = c0 + c;
    const float* s = src + ((size_t)(bb * 512 + kt * 32 + ck * 8)) * C + cg;

    h8_t hi, lo;
    #pragma unroll
    for (int j = 0; j < 8; ++j) {
        float v = s[(size_t)j * C] * 64.0f;   // 2^6 pre-scale
        _Float16 hh = (_Float16)v;
        hi[j] = hh;
        lo[j] = (_Float16)(v - (float)hh);    // exact residual, fp16-rounded
    }
    const int ckp = ck ^ ((cg >> 1) & 3);
    const size_t off = ((size_t)(bb * 16 + kt) * C + cg) * 32 + ckp * 8;
    *(h8_t*)(dhi + off) = hi;
    *(h8_t*)(dlo + off) = lo;
}

// ---------------- main fused kernel ----------------
__global__ __launch_bounds__(512, 2) void fused_main(
    const _Float16* __restrict__ xhi, const _Float16* __restrict__ xlo,
    const _Float16* __restrict__ whi, const _Float16* __restrict__ wlo,
    const float* __restrict__ bias, float* __restrict__ out)
{
    __shared__ __align__(16) _Float16 Ahi[TB * KK];  // 16 KB
    __shared__ __align__(16) _Float16 Alo[TB * KK];  // 16 KB
    __shared__ __align__(16) _Float16 Bhi[HB * KK];  // 16 KB
    __shared__ __align__(16) _Float16 Blo[HB * KK];  // 16 KB
    __shared__ float P[2][64][132];                  // 67,584 B; total 133,120

    const int tid  = threadIdx.x;
    const int lane = tid & 63;
    const int wid  = tid >> 6;     // 0..7
    const int l15  = lane & 15;
    const int lq   = lane >> 4;    // 0..3
    const int wm   = wid >> 1;     // t quarter 0..3
    const int wn   = wid & 1;      // h half 0..1

    const int b  = blockIdx.x;
    const int h0 = blockIdx.y * HB;

    // fragment LDS offsets (halfs); chunk swizzle matches pre-pass
    const int sw   = (l15 >> 1) & 3;
    const int aoff = ((wm * 64 + l15) * 4 + (lq ^ sw)) * 8;   // + mi*512
    const int boff = ((wn * 128 + l15) * 4 + (lq ^ sw)) * 8;  // + ni*512

    float hs = 0.0f, ys = 0.0f, bv = 0.0f;
    if (tid < HB) bv = bias[h0 + tid];

    const float INV_SCALE = 1.0f / 4096.0f;   // undo 2^6 x 2^6 operand scales

    // stage tile (tt, kt): 4 arrays x 1024 16B-chunks, 512 threads x 2.
    // LDS dest = wave-uniform base + lane*16 (global_load_lds constraint).
    auto stage = [&](int tt, int kt) {
        const _Float16* ga_hi = xhi + ((size_t)(b * 16 + kt) * NT + tt) * KK;
        const _Float16* ga_lo = xlo + ((size_t)(b * 16 + kt) * NT + tt) * KK;
        const _Float16* gb_hi = whi + ((size_t)kt * NH + h0) * KK;
        const _Float16* gb_lo = wlo + ((size_t)kt * NH + h0) * KK;
        #pragma unroll
        for (int c = 0; c < 2; ++c) {
            const int ch = tid + c * 512;
            async_copy16(ga_hi + ch * 8, &Ahi[ch * 8]);
            async_copy16(ga_lo + ch * 8, &Alo[ch * 8]);
            async_copy16(gb_hi + ch * 8, &Bhi[ch * 8]);
            async_copy16(gb_lo + ch * 8, &Blo[ch * 8]);
        }
    };

    f4_t acc[4][8];

    for (int tt0 = 0; tt0 < NT; tt0 += TB) {
        #pragma unroll
        for (int mi = 0; mi < 4; ++mi)
            #pragma unroll
            for (int ni = 0; ni < 8; ++ni) {
                f4_t z = {0.f, 0.f, 0.f, 0.f};
                acc[mi][ni] = z;
            }

        for (int kt = 0; kt < NK / KK; ++kt) {
            stage(tt0, kt);       // R2-proven shape: stage at top...
            wait_all_barrier();   // ...drain + barrier, then consume

            h8_t bh[8], bl[8];
            #pragma unroll
            for (int ni = 0; ni < 8; ++ni) {
                bh[ni] = *(const h8_t*)(&Bhi[boff + ni * 512]);
                bl[ni] = *(const h8_t*)(&Blo[boff + ni * 512]);
            }
            #pragma unroll
            for (int mi = 0; mi < 4; ++mi) {
                h8_t ah = *(const h8_t*)(&Ahi[aoff + mi * 512]);
                h8_t al = *(const h8_t*)(&Alo[aoff + mi * 512]);
                #pragma unroll
                for (int ni = 0; ni < 8; ++ni) {
                    acc[mi][ni] = __builtin_amdgcn_mfma_f32_16x16x32_f16(ah, bh[ni], acc[mi][ni], 0, 0, 0);
                    acc[mi][ni] = __builtin_amdgcn_mfma_f32_16x16x32_f16(ah, bl[ni], acc[mi][ni], 0, 0, 0);
                    acc[mi][ni] = __builtin_amdgcn_mfma_f32_16x16x32_f16(al, bh[ni], acc[mi][ni], 0, 0, 0);
                }
            }

            wait_all_barrier();   // all lanes' frag reads done before next stage
        }

        // epilogue: 4 t-subtiles x 64; both h-halves concurrently (P[0],P[1])
        #pragma unroll 1
        for (int sub = 0; sub < 4; ++sub) {
            if (wm == sub) {
                float (*Pb)[132] = P[wn];
                #pragma unroll
                for (int mi = 0; mi < 4; ++mi)
                    #pragma unroll
                    for (int ni = 0; ni < 8; ++ni)
                        #pragma unroll
                        for (int r = 0; r < 4; ++r)
                            Pb[mi * 16 + lq * 4 + r][ni * 16 + l15] = acc[mi][ni][r] * INV_SCALE;
            }
            __syncthreads();
            if (tid < HB) {
                const float (*Pb)[132] = P[tid >> 7];
                const int c = tid & 127;
                #pragma unroll 8
                for (int m = 0; m < 64; ++m) {
                    float p = Pb[m][c];
                    float pre = p + 0.8f * hs * (1.0f - ys);
                    hs = pre > 0.0f ? pre : 0.0f;
                    float z = hs + bv;
                    ys = (z > 1.0f) ? z : 0.0f;
                }
            }
            __syncthreads();   // scan done before next sub overwrites P
        }
    }

    if (tid < HB)
        out[(size_t)b * NH + h0 + tid] = ys;
}

extern "C" void kernel_launch(void* const* d_in, const int* in_sizes, int n_in,
                              void* d_out, int out_size, void* d_ws, size_t ws_size,
                              hipStream_t stream) {
    const float* x    = (const float*)d_in[0];  // [64][512][512]
    const float* W    = (const float*)d_in[1];  // [512][1024]
    const float* bias = (const float*)d_in[2];  // [1024]
    float* out = (float*)d_out;

    _Float16* xhi = (_Float16*)d_ws;
    _Float16* xlo = xhi + (size_t)NB * NK * NT;
    _Float16* whi = xlo + (size_t)NB * NK * NT;
    _Float16* wlo = whi + (size_t)NK * NH;

    split_fragorder<<<dim3(NT / 64, NK / 32, NB), 256, 0, stream>>>(x, xhi, xlo, NT);
    split_fragorder<<<dim3(NH / 64, NK / 32, 1), 256, 0, stream>>>(W, whi, wlo, NH);
    fused_main<<<dim3(NB, NH / HB), 512, 0, stream>>>(xhi, xlo, whi, wlo, bias, out);
}